// Round 1
// baseline (117.880 us; speedup 1.0000x reference)
//
#include <hip/hip_runtime.h>
#include <cmath>

#define TT 1024
#define BB 8
#define IND 512
#define NCHUNK 32
#define CHLEN 32          // TT / NCHUNK
#define EPSV 1e-8
#define OUTHALF ((size_t)TT * BB * 4096)

// ---------------- K1: projections v,k,alpha  (f32 GEMM, f64 chunk-combine) -----
__global__ __launch_bounds__(256)
void k1_proj(const float* __restrict__ x,
             const float* __restrict__ Wv, const float* __restrict__ bv,
             const float* __restrict__ Wk, const float* __restrict__ bk,
             const float* __restrict__ Wa, const float* __restrict__ ba,
             float* __restrict__ vOut, float* __restrict__ kOut,
             double* __restrict__ aOut)
{
    __shared__ float sWt[64][192];   // 48 KB, transposed weight chunk
    __shared__ float sXt[64][16];    // 4 KB,  transposed x chunk
    const int tid = threadIdx.x;
    const int rowbase = blockIdx.x * 16;          // 512 blocks * 16 rows = 8192
    const int c0 = tid & 63;                      // output col within each matrix
    const int r0 = (tid >> 6) << 2;               // 4 rows per wave
    double a0[4] = {0,0,0,0}, a1[4] = {0,0,0,0}, a2[4] = {0,0,0,0};

    for (int ko = 0; ko < IND; ko += 64) {
        __syncthreads();
        if (tid < 192) {
            const float* src;
            if (tid < 64)       src = Wv + (size_t)tid * IND;
            else if (tid < 128) src = Wk + (size_t)(tid - 64) * IND;
            else                src = Wa + (size_t)(tid - 128) * IND;
            src += ko;
            #pragma unroll
            for (int q = 0; q < 64; q += 4) {
                float4 w4 = *(const float4*)(src + q);
                sWt[q+0][tid] = w4.x; sWt[q+1][tid] = w4.y;
                sWt[q+2][tid] = w4.z; sWt[q+3][tid] = w4.w;
            }
        }
        {
            int r  = tid & 15;
            int kq = (tid >> 4) << 2;
            float4 x4 = *(const float4*)(x + (size_t)(rowbase + r) * IND + ko + kq);
            sXt[kq+0][r] = x4.x; sXt[kq+1][r] = x4.y;
            sXt[kq+2][r] = x4.z; sXt[kq+3][r] = x4.w;
        }
        __syncthreads();

        float f0[4] = {0,0,0,0}, f1[4] = {0,0,0,0}, f2[4] = {0,0,0,0};
        #pragma unroll
        for (int q = 0; q < 64; ++q) {
            float4 xv = *(const float4*)&sXt[q][r0];   // wave-uniform broadcast
            float w0 = sWt[q][c0], w1 = sWt[q][c0 + 64], w2 = sWt[q][c0 + 128];
            f0[0] = fmaf(xv.x, w0, f0[0]); f1[0] = fmaf(xv.x, w1, f1[0]); f2[0] = fmaf(xv.x, w2, f2[0]);
            f0[1] = fmaf(xv.y, w0, f0[1]); f1[1] = fmaf(xv.y, w1, f1[1]); f2[1] = fmaf(xv.y, w2, f2[1]);
            f0[2] = fmaf(xv.z, w0, f0[2]); f1[2] = fmaf(xv.z, w1, f1[2]); f2[2] = fmaf(xv.z, w2, f2[2]);
            f0[3] = fmaf(xv.w, w0, f0[3]); f1[3] = fmaf(xv.w, w1, f1[3]); f2[3] = fmaf(xv.w, w2, f2[3]);
        }
        #pragma unroll
        for (int i = 0; i < 4; ++i) { a0[i] += f0[i]; a1[i] += f1[i]; a2[i] += f2[i]; }
    }

    #pragma unroll
    for (int i = 0; i < 4; ++i) {
        int r = rowbase + r0 + i;
        vOut[r * 64 + c0] = (float)(a0[i] + (double)bv[c0]);
        kOut[r * 64 + c0] = (float)(a1[i] + (double)bk[c0]);
        double z = a2[i] + (double)ba[c0];
        aOut[r * 64 + c0] = 1.0 / (1.0 + exp(-z));
    }
}

// ---------------- K2a: per-chunk alpha products --------------------------------
__global__ __launch_bounds__(256)
void k2a_chunkprod(const double* __restrict__ alpha, double* __restrict__ cpA)
{
    int gt = blockIdx.x * 256 + threadIdx.x;      // 0..16383 = 32 chunks * 512 chains
    int ch = gt >> 9, chain = gt & 511;
    int b = chain >> 6, n = chain & 63;
    double p = 1.0;
    int base = ((ch * CHLEN) * BB + b) * 64 + n;
    for (int i = 0; i < CHLEN; ++i) p *= alpha[base + i * 512];
    cpA[gt] = p;
}

// ---------------- K2b: exclusive prefix product over chunks --------------------
__global__ __launch_bounds__(512)
void k2b_prefix(double* __restrict__ cpA)
{
    int chain = threadIdx.x;                      // 512 threads, 1 block
    double run = 1.0;
    for (int ch = 0; ch < NCHUNK; ++ch) {
        double t = cpA[ch * 512 + chain];
        cpA[ch * 512 + chain] = run;
        run *= t;
    }
}

// ---------------- K3: per-chunk partial C sums (no output writes) --------------
__global__ __launch_bounds__(256)
void k3_csum(const float* __restrict__ vIn, const float* __restrict__ kIn,
             const double* __restrict__ alpha, const double* __restrict__ cpA,
             double* __restrict__ Csum)
{
    __shared__ double sV[CHLEN * 64];             // 16 KB
    const int tid = threadIdx.x;
    const int ch = blockIdx.x >> 3;
    const int b  = blockIdx.x & 7;
    #pragma unroll
    for (int q = 0; q < 8; ++q) {
        int idx = q * 256 + tid;
        int ti = idx >> 6, d = idx & 63;
        sV[idx] = (double)vIn[(((ch * CHLEN + ti) * BB) + b) * 64 + d];
    }
    __syncthreads();
    const int n = tid & 63;
    const int w = tid >> 6;
    double P = cpA[ch * 512 + b * 64 + n];
    double C[16];
    #pragma unroll
    for (int j = 0; j < 16; ++j) C[j] = 0.0;
    for (int i = 0; i < CHLEN; ++i) {
        int base = ((ch * CHLEN + i) * BB + b) * 64 + n;
        P *= alpha[base];
        double invp = 1.0 / (P + EPSV);
        double kd = (double)kIn[base] * invp;
        const double* vrow = &sV[i * 64 + w * 16];
        #pragma unroll
        for (int j = 0; j < 16; ++j) C[j] = fma(vrow[j], kd, C[j]);
    }
    size_t cb = ((size_t)ch * 8 + b) * 4096 + (size_t)w * 1024 + n;
    #pragma unroll
    for (int j = 0; j < 16; ++j) Csum[cb + j * 64] = C[j];
}

// ---------------- K3b: exclusive prefix sum of chunk partials ------------------
__global__ __launch_bounds__(256)
void k3b_prefix(double* __restrict__ Csum)
{
    int s = blockIdx.x * 256 + threadIdx.x;       // 0..32767 chains
    int b = s >> 12, rest = s & 4095;
    double run = 0.0;
    for (int ch = 0; ch < NCHUNK; ++ch) {
        size_t idx = ((size_t)ch * 8 + b) * 4096 + rest;
        double t = Csum[idx];
        Csum[idx] = run;
        run += t;
    }
}

// ---------------- K4: main scan, writes spk + mem ------------------------------
__global__ __launch_bounds__(256)
void k4_scan(const float* __restrict__ vIn, const float* __restrict__ kIn,
             const double* __restrict__ alpha, const double* __restrict__ cpA,
             const double* __restrict__ Csum, float* __restrict__ outp)
{
    __shared__ double sV[CHLEN * 64];
    const int tid = threadIdx.x;
    const int ch = blockIdx.x >> 3;
    const int b  = blockIdx.x & 7;
    #pragma unroll
    for (int q = 0; q < 8; ++q) {
        int idx = q * 256 + tid;
        int ti = idx >> 6, d = idx & 63;
        sV[idx] = (double)vIn[(((ch * CHLEN + ti) * BB) + b) * 64 + d];
    }
    __syncthreads();
    const int n = tid & 63;
    const int w = tid >> 6;
    double P = cpA[ch * 512 + b * 64 + n];
    size_t cb = ((size_t)ch * 8 + b) * 4096 + (size_t)w * 1024 + n;
    double C[16];
    #pragma unroll
    for (int j = 0; j < 16; ++j) C[j] = Csum[cb + j * 64];

    float* spk = outp;
    float* mem = outp + OUTHALF;
    for (int i = 0; i < CHLEN; ++i) {
        int t = ch * CHLEN + i;
        int base = (t * BB + b) * 64 + n;
        P *= alpha[base];
        double invp = 1.0 / (P + EPSV);
        double kd = (double)kIn[base] * invp;
        double vd[16];
        const double* vrow = &sV[i * 64 + w * 16];
        #pragma unroll
        for (int j = 0; j < 16; ++j) vd[j] = vrow[j];
        size_t ob = ((size_t)t * BB + b) * 4096 + (size_t)w * 1024 + n;
        #pragma unroll
        for (int j = 0; j < 16; ++j) {
            C[j] = fma(vd[j], kd, C[j]);
            double S = P * C[j];
            mem[ob + j * 64] = (float)S;
            spk[ob + j * 64] = (S > 1.0) ? 1.0f : 0.0f;
        }
    }
}

// ---------------- launch -------------------------------------------------------
extern "C" void kernel_launch(void* const* d_in, const int* in_sizes, int n_in,
                              void* d_out, int out_size, void* d_ws, size_t ws_size,
                              hipStream_t stream)
{
    const float* x  = (const float*)d_in[0];
    const float* Wv = (const float*)d_in[1];
    const float* bv = (const float*)d_in[2];
    const float* Wk = (const float*)d_in[3];
    const float* bk = (const float*)d_in[4];
    const float* Wa = (const float*)d_in[5];
    const float* ba = (const float*)d_in[6];
    float* out = (float*)d_out;

    char* ws = (char*)d_ws;
    float*  v     = (float*)(ws);                                   // 2 MB
    float*  kk    = (float*)(ws + (2u << 20));                      // 2 MB
    double* alpha = (double*)(ws + (4u << 20));                     // 4 MB
    double* cpA   = (double*)(ws + (8u << 20));                     // 128 KB
    double* Csum  = (double*)(ws + (8u << 20) + (1u << 17));        // 8 MB

    hipLaunchKernelGGL(k1_proj,      dim3(512), dim3(256), 0, stream,
                       x, Wv, bv, Wk, bk, Wa, ba, v, kk, alpha);
    hipLaunchKernelGGL(k2a_chunkprod, dim3(64), dim3(256), 0, stream, alpha, cpA);
    hipLaunchKernelGGL(k2b_prefix,    dim3(1),  dim3(512), 0, stream, cpA);
    hipLaunchKernelGGL(k3_csum,       dim3(256), dim3(256), 0, stream,
                       v, kk, alpha, cpA, Csum);
    hipLaunchKernelGGL(k3b_prefix,    dim3(128), dim3(256), 0, stream, Csum);
    hipLaunchKernelGGL(k4_scan,       dim3(256), dim3(256), 0, stream,
                       v, kk, alpha, cpA, Csum, out);
}